// Round 18
// baseline (54.558 us; speedup 1.0000x reference)
//
#include <hip/hip_runtime.h>
#include <float.h>

#define NB 8
#define NN 2048
#define ROWS (NB*NN)   // 16384
#define JSPLIT 8
#define JRANGE (NN/JSPLIT)   // 256
#define CHUNK 64
#define NTILE (CHUNK/16)     // 4

typedef _Float16 half8 __attribute__((ext_vector_type(8)));
typedef _Float16 half4 __attribute__((ext_vector_type(4)));
typedef float f32x4 __attribute__((ext_vector_type(4)));
typedef unsigned long long u64;

// monotone f32 -> u32 (order-preserving for all finite floats)
__device__ __forceinline__ unsigned ordf(float f) {
  unsigned u = __float_as_uint(f);
  return (u & 0x80000000u) ? ~u : (u | 0x80000000u);
}

// ---------------- Kernel 1: q,k,v = x @ [Wq|Wkv] via f16 split-3 MFMA ------
// R17 body + emits packed k hi/lo (khl[row][dq] = {hi4,lo4}) so argmax
// needs zero convert VALU. Conversion inputs/ops identical -> same f16 bits.
__global__ __launch_bounds__(256) void qkv_kernel(
    const float* __restrict__ x, const float* __restrict__ Wq,
    const float* __restrict__ Wkv,
    float* __restrict__ q, float* __restrict__ k, float* __restrict__ v,
    _Float16* __restrict__ khl) {
  __shared__ float stage[32*196];   // [r_local][c 0..191], 25KB
  const int tid = threadIdx.x, lane = tid & 63, wv = tid >> 6;
  const int li = lane & 15, lg = lane >> 4;
  const size_t r0 = (size_t)blockIdx.x * 32;
  half8 xh[2][2], xl[2][2];
#pragma unroll
  for (int rt = 0; rt < 2; ++rt)
#pragma unroll
    for (int kh_ = 0; kh_ < 2; ++kh_) {
      const float* src = x + (r0 + rt*16 + li)*64 + kh_*32 + lg*8;
      float4 f0 = *(const float4*)src;
      float4 f1 = *(const float4*)(src+4);
      float vals[8] = {f0.x,f0.y,f0.z,f0.w,f1.x,f1.y,f1.z,f1.w};
#pragma unroll
      for (int e = 0; e < 8; ++e) {
        _Float16 h = (_Float16)vals[e];
        xh[rt][kh_][e] = h;
        xl[rt][kh_][e] = (_Float16)((vals[e] - (float)h) * 2048.0f);
      }
    }
  half8 wh[3][2], wl[3][2];
#pragma unroll
  for (int ci = 0; ci < 3; ++ci) {
    const int ct = wv*3 + ci;
    const int c  = ct*16 + li;
    const float* base; int strideW;
    if (ct < 4) { base = Wq + c; strideW = 64; }
    else        { base = Wkv + (c - 64); strideW = 128; }
#pragma unroll
    for (int kh_ = 0; kh_ < 2; ++kh_) {
      const int kbase = kh_*32 + lg*8;
#pragma unroll
      for (int e = 0; e < 8; ++e) {
        float val = base[(size_t)(kbase + e) * strideW];
        _Float16 h = (_Float16)val;
        wh[ci][kh_][e] = h;
        wl[ci][kh_][e] = (_Float16)((val - (float)h) * 2048.0f);
      }
    }
  }
  const f32x4 Z = {0.f,0.f,0.f,0.f};
#pragma unroll
  for (int rt = 0; rt < 2; ++rt)
#pragma unroll
    for (int ci = 0; ci < 3; ++ci) {
      f32x4 hh = __builtin_amdgcn_mfma_f32_16x16x32_f16(wh[ci][0], xh[rt][0], Z, 0,0,0);
      hh = __builtin_amdgcn_mfma_f32_16x16x32_f16(wh[ci][1], xh[rt][1], hh, 0,0,0);
      f32x4 xx = __builtin_amdgcn_mfma_f32_16x16x32_f16(wl[ci][0], xh[rt][0], Z, 0,0,0);
      xx = __builtin_amdgcn_mfma_f32_16x16x32_f16(wl[ci][1], xh[rt][1], xx, 0,0,0);
      xx = __builtin_amdgcn_mfma_f32_16x16x32_f16(wh[ci][0], xl[rt][0], xx, 0,0,0);
      xx = __builtin_amdgcn_mfma_f32_16x16x32_f16(wh[ci][1], xl[rt][1], xx, 0,0,0);
      const float c2 = 1.0f/2048.0f;
      float s0 = fmaf(xx[0], c2, hh[0]);
      float s1 = fmaf(xx[1], c2, hh[1]);
      float s2 = fmaf(xx[2], c2, hh[2]);
      float s3 = fmaf(xx[3], c2, hh[3]);
      *(float4*)&stage[(rt*16 + li)*196 + (wv*3+ci)*16 + lg*4] = make_float4(s0,s1,s2,s3);
    }
  __syncthreads();
  const size_t obase = r0 * 64;
#pragma unroll
  for (int it = 0; it < 2; ++it) {
    const int off = it*1024 + tid*4;
    const int row = off >> 6, col = off & 63;
    *(float4*)(q + obase + off) = *(const float4*)&stage[row*196 + col];
    float4 kv4 = *(const float4*)&stage[row*196 + 64 + col];
    *(float4*)(k + obase + off) = kv4;
    *(float4*)(v + obase + off) = *(const float4*)&stage[row*196 + 128 + col];
    // packed hi/lo k: identical convert arithmetic as R17's argmax staging
    float kvals[4] = {kv4.x, kv4.y, kv4.z, kv4.w};
    half8 pk8;
#pragma unroll
    for (int e = 0; e < 4; ++e) {
      _Float16 h = (_Float16)kvals[e];
      pk8[e]   = h;
      pk8[4+e] = (_Float16)((kvals[e] - (float)h) * 2048.0f);
    }
    *(half8*)(khl + (size_t)(obase + off)*2) = pk8;   // row*128 + (col/4)*8
  }
}

// ---------------- Kernel 2: argmax — R17 body, pre-split staging (no VALU) --
__global__ __launch_bounds__(256,4) void argmax_mfma_kernel(
    const float* __restrict__ q, const _Float16* __restrict__ khl,
    u64* __restrict__ pk) {
  __shared__ _Float16 kls[2][8][CHUNK][8];   // [term][d0][j][e] = 16KB
  const int tid = threadIdx.x, lane = tid & 63, wv = tid >> 6;
  const int id = blockIdx.x;
  const int b  = id & 7;              // XCD pin: batch b -> XCD b
  const int ib = (id >> 3) & 7;
  const int js = id >> 6;
  const int i0 = ib*256 + wv*64;      // wave covers 64 i (4 tiles of 16)
  const int lg = lane >> 4, li = lane & 15;
  half8 qh[4][2], ql[4][2];
#pragma unroll
  for (int c = 0; c < 4; ++c)
#pragma unroll
    for (int w = 0; w < 2; ++w) {
      const float* src = q + ((size_t)(b*NN + i0 + c*16 + li))*64 + w*32 + lg*8;
      float4 f0 = *(const float4*)src;
      float4 f1 = *(const float4*)(src+4);
      float vals[8] = {f0.x,f0.y,f0.z,f0.w,f1.x,f1.y,f1.z,f1.w};
#pragma unroll
      for (int e = 0; e < 8; ++e) {
        _Float16 h = (_Float16)vals[e];
        qh[c][w][e] = h;
        ql[c][w][e] = (_Float16)((vals[e] - (float)h) * 2048.0f);
      }
    }
  const f32x4 Z = {0.f,0.f,0.f,0.f};
  float mrun[4] = {-FLT_MAX, -FLT_MAX, -FLT_MAX, -FLT_MAX};
  int   trun[4] = {0, 0, 0, 0};
  const int j0base = js*JRANGE;
#pragma unroll 1
  for (int ch = 0; ch < JRANGE/CHUNK; ++ch) {
    const int j0 = j0base + ch*CHUNK;
    __syncthreads();
#pragma unroll
    for (int it = 0; it < 4; ++it) {     // R11 mapping; pure load->write now
      int c = it*256 + tid;
      int j = c & 63, dq = c >> 6;
      half8 pk8 = *(const half8*)(khl + ((size_t)(b*NN + j0 + j))*128 + dq*8);
      half4 h4, l4;
      h4[0]=pk8[0]; h4[1]=pk8[1]; h4[2]=pk8[2]; h4[3]=pk8[3];
      l4[0]=pk8[4]; l4[1]=pk8[5]; l4[2]=pk8[6]; l4[3]=pk8[7];
      int d0 = dq >> 1, eo = (dq & 1)*4;
      *(half4*)&kls[0][d0][j][eo] = h4;
      *(half4*)&kls[1][d0][j][eo] = l4;
    }
    __syncthreads();
#pragma unroll
    for (int jt = 0; jt < NTILE; ++jt) {
      half8 akh0 = *(const half8*)&kls[0][lg  ][jt*16+li][0];
      half8 akh1 = *(const half8*)&kls[0][4+lg][jt*16+li][0];
      half8 akl0 = *(const half8*)&kls[1][lg  ][jt*16+li][0];
      half8 akl1 = *(const half8*)&kls[1][4+lg][jt*16+li][0];
      const int gtile = j0/16 + jt;
#pragma unroll
      for (int c = 0; c < 4; ++c) {
        f32x4 hh = __builtin_amdgcn_mfma_f32_16x16x32_f16(akh0, qh[c][0], Z, 0,0,0);
        hh = __builtin_amdgcn_mfma_f32_16x16x32_f16(akh1, qh[c][1], hh, 0,0,0);
        f32x4 xx = __builtin_amdgcn_mfma_f32_16x16x32_f16(akl0, qh[c][0], Z, 0,0,0);
        xx = __builtin_amdgcn_mfma_f32_16x16x32_f16(akl1, qh[c][1], xx, 0,0,0);
        xx = __builtin_amdgcn_mfma_f32_16x16x32_f16(akh0, ql[c][0], xx, 0,0,0);
        xx = __builtin_amdgcn_mfma_f32_16x16x32_f16(akh1, ql[c][1], xx, 0,0,0);
        const float c2 = 1.0f/2048.0f;
        float s0 = fmaf(xx[0], c2, hh[0]);
        float s1 = fmaf(xx[1], c2, hh[1]);
        float s2 = fmaf(xx[2], c2, hh[2]);
        float s3 = fmaf(xx[3], c2, hh[3]);
        float tmax = fmaxf(fmaxf(s0,s1), fmaxf(s2,s3));
        if (tmax > mrun[c]) { mrun[c] = tmax; trun[c] = gtile; }  // strict >: lowest tile kept
      }
    }
  }
  u64 key[4];
#pragma unroll
  for (int c = 0; c < 4; ++c)
    key[c] = ((u64)ordf(mrun[c]) << 32) | (unsigned)(127 - trun[c]);
#pragma unroll
  for (int c = 0; c < 4; ++c) {
#pragma unroll
    for (int mask = 16; mask <= 32; mask <<= 1) {
      u64 ok = __shfl_xor(key[c], mask, 64);
      if (ok > key[c]) key[c] = ok;
    }
  }
  {
    const size_t rb = (size_t)js*ROWS + b*NN + i0 + li;
    if (lg == 0)      pk[rb]      = key[0];
    else if (lg == 1) pk[rb + 16] = key[1];
    else if (lg == 2) pk[rb + 32] = key[2];
    else              pk[rb + 48] = key[3];
  }
}

// ---------------- Kernel 3: fused rescue + epilogue (exact R17 version) -----
__global__ __launch_bounds__(256) void epilogue_kernel(
    const float* __restrict__ x, const float* __restrict__ v,
    const float* __restrict__ q, const float* __restrict__ k,
    const u64* __restrict__ pk,
    const float* __restrict__ g1, const float* __restrict__ b1,
    const float* __restrict__ W1, const float* __restrict__ bin,
    const float* __restrict__ W2, const float* __restrict__ bout,
    const float* __restrict__ g2, const float* __restrict__ b2,
    float* __restrict__ out) {
  __shared__ float mids[16*68];
  __shared__ float2 sums[16*4];
  __shared__ int sidx[32];
  const int tid = threadIdx.x, lane = tid & 63, wv = tid >> 6;
  const int li = lane & 15, lg = lane >> 4;
  const int bid = blockIdx.x;
  const size_t r0 = (size_t)(bid & 7)*NN + (size_t)(bid >> 3)*32;

#pragma unroll
  for (int rnd = 0; rnd < 2; ++rnd) {
    const int rloc = rnd*16 + wv*4 + lg;
    const int row  = (int)r0 + rloc;
    const int b    = row >> 11;
    u64 key = 0ULL;
    if (li < 8) key = pk[(size_t)li*ROWS + row];
#pragma unroll
    for (int mask = 1; mask <= 8; mask <<= 1) {
      u64 ok = __shfl_xor(key, mask, 64);
      if (ok > key) key = ok;
    }
    const int t = 127 - (int)(unsigned)(key & 0xFFFFFFFFu);
    const int j = t*16 + li;
    const float4* qp = (const float4*)(q + (size_t)row*64);
    const float4* kp = (const float4*)(k + ((size_t)(b*NN) + j)*64);
    float a0=0.f,a1=0.f,a2=0.f,a3=0.f;
#pragma unroll
    for (int d4 = 0; d4 < 16; ++d4) {
      float4 qv = qp[d4], kv = kp[d4];
      a0 = fmaf(qv.x,kv.x,a0); a1 = fmaf(qv.y,kv.y,a1);
      a2 = fmaf(qv.z,kv.z,a2); a3 = fmaf(qv.w,kv.w,a3);
    }
    float dot = (a0+a1)+(a2+a3);
    int bj = j;
#pragma unroll
    for (int mask = 1; mask <= 8; mask <<= 1) {
      float od = __shfl_xor(dot, mask, 64);
      int   oj = __shfl_xor(bj, mask, 64);
      if (od > dot || (od == dot && oj < bj)) { dot = od; bj = oj; }  // first max
    }
    if (li == 0) sidx[rloc] = bj;
  }

  half8 wah[2], wal[2], wbh[2], wbl[2], w2h[2], w2l[2];
  const int ocol = wv*16 + li;
#pragma unroll
  for (int kh_ = 0; kh_ < 2; ++kh_) {
#pragma unroll
    for (int e = 0; e < 8; ++e) {
      const int d = kh_*32 + lg*8 + e;
      float wa = W1[d*64 + ocol] + W1[(128+d)*64 + ocol];
      float wb = W1[(64+d)*64 + ocol];
      float w2 = W2[d*64 + ocol];
      _Float16 h;
      h = (_Float16)wa; wah[kh_][e]=h; wal[kh_][e]=(_Float16)((wa-(float)h)*2048.f);
      h = (_Float16)wb; wbh[kh_][e]=h; wbl[kh_][e]=(_Float16)((wb-(float)h)*2048.f);
      h = (_Float16)w2; w2h[kh_][e]=h; w2l[kh_][e]=(_Float16)((w2-(float)h)*2048.f);
    }
  }
  float ga[16], bb[16];
  *(float4*)&ga[0]  = *(const float4*)(g1 + lg*8);
  *(float4*)&ga[4]  = *(const float4*)(g1 + lg*8 + 4);
  *(float4*)&ga[8]  = *(const float4*)(g1 + 32 + lg*8);
  *(float4*)&ga[12] = *(const float4*)(g1 + 32 + lg*8 + 4);
  *(float4*)&bb[0]  = *(const float4*)(b1 + lg*8);
  *(float4*)&bb[4]  = *(const float4*)(b1 + lg*8 + 4);
  *(float4*)&bb[8]  = *(const float4*)(b1 + 32 + lg*8);
  *(float4*)&bb[12] = *(const float4*)(b1 + 32 + lg*8 + 4);
  const float4 binv  = *(const float4*)(bin + wv*16 + lg*4);
  const float4 boutv = *(const float4*)(bout + wv*16 + lg*4);
  const float4 g2v   = *(const float4*)(g2 + wv*16 + lg*4);
  const float4 b2v   = *(const float4*)(b2 + wv*16 + lg*4);
  __syncthreads();   // sidx ready

  const f32x4 Z = {0.f,0.f,0.f,0.f};
  const float c2 = 1.0f/2048.0f;
#pragma unroll 1
  for (int p = 0; p < 2; ++p) {
    const int rr = (int)r0 + p*16 + li;
    const int b  = rr >> 11;
    const int j  = sidx[p*16 + li];
    const float* vsrc = v + ((size_t)b*NN + j)*64 + lg*8;
    const float* xsrc = x + (size_t)rr*64 + lg*8;
    float vv[16], xv[16];
    *(float4*)&vv[0]  = *(const float4*)(vsrc);
    *(float4*)&vv[4]  = *(const float4*)(vsrc+4);
    *(float4*)&vv[8]  = *(const float4*)(vsrc+32);
    *(float4*)&vv[12] = *(const float4*)(vsrc+36);
    *(float4*)&xv[0]  = *(const float4*)(xsrc);
    *(float4*)&xv[4]  = *(const float4*)(xsrc+4);
    *(float4*)&xv[8]  = *(const float4*)(xsrc+32);
    *(float4*)&xv[12] = *(const float4*)(xsrc+36);
    float s = 0.f, s2 = 0.f;
#pragma unroll
    for (int e = 0; e < 16; ++e) { s += vv[e]; s2 += vv[e]*vv[e]; }
#pragma unroll
    for (int mask = 16; mask <= 32; mask <<= 1) {
      s  += __shfl_xor(s,  mask, 64);
      s2 += __shfl_xor(s2, mask, 64);
    }
    float mu  = s*(1.f/64.f);
    float inv = rsqrtf(s2*(1.f/64.f) - mu*mu + 1e-5f);
    half8 nh[2], nl[2], xh[2], xl[2];
#pragma unroll
    for (int kh_ = 0; kh_ < 2; ++kh_)
#pragma unroll
      for (int e = 0; e < 8; ++e) {
        float nvv = (vv[kh_*8+e] - mu)*inv*ga[kh_*8+e] + bb[kh_*8+e];
        _Float16 h = (_Float16)nvv;
        nh[kh_][e] = h; nl[kh_][e] = (_Float16)((nvv - (float)h)*2048.f);
        float xvv = xv[kh_*8+e];
        h = (_Float16)xvv;
        xh[kh_][e] = h; xl[kh_][e] = (_Float16)((xvv - (float)h)*2048.f);
      }
    f32x4 hh = __builtin_amdgcn_mfma_f32_16x16x32_f16(wah[0], nh[0], Z, 0,0,0);
    hh = __builtin_amdgcn_mfma_f32_16x16x32_f16(wah[1], nh[1], hh, 0,0,0);
    hh = __builtin_amdgcn_mfma_f32_16x16x32_f16(wbh[0], xh[0], hh, 0,0,0);
    hh = __builtin_amdgcn_mfma_f32_16x16x32_f16(wbh[1], xh[1], hh, 0,0,0);
    f32x4 xx = __builtin_amdgcn_mfma_f32_16x16x32_f16(wal[0], nh[0], Z, 0,0,0);
    xx = __builtin_amdgcn_mfma_f32_16x16x32_f16(wal[1], nh[1], xx, 0,0,0);
    xx = __builtin_amdgcn_mfma_f32_16x16x32_f16(wah[0], nl[0], xx, 0,0,0);
    xx = __builtin_amdgcn_mfma_f32_16x16x32_f16(wah[1], nl[1], xx, 0,0,0);
    xx = __builtin_amdgcn_mfma_f32_16x16x32_f16(wbl[0], xh[0], xx, 0,0,0);
    xx = __builtin_amdgcn_mfma_f32_16x16x32_f16(wbl[1], xh[1], xx, 0,0,0);
    xx = __builtin_amdgcn_mfma_f32_16x16x32_f16(wbh[0], xl[0], xx, 0,0,0);
    xx = __builtin_amdgcn_mfma_f32_16x16x32_f16(wbh[1], xl[1], xx, 0,0,0);
    float mv0 = fmaxf(fmaf(xx[0], c2, hh[0]) + binv.x, 0.f);
    float mv1 = fmaxf(fmaf(xx[1], c2, hh[1]) + binv.y, 0.f);
    float mv2 = fmaxf(fmaf(xx[2], c2, hh[2]) + binv.z, 0.f);
    float mv3 = fmaxf(fmaf(xx[3], c2, hh[3]) + binv.w, 0.f);
    *(float4*)&mids[li*68 + wv*16 + lg*4] = make_float4(mv0,mv1,mv2,mv3);
    __syncthreads();
    half8 mh[2], ml[2];
#pragma unroll
    for (int kh_ = 0; kh_ < 2; ++kh_) {
      float mm[8];
      *(float4*)&mm[0] = *(const float4*)&mids[li*68 + kh_*32 + lg*8];
      *(float4*)&mm[4] = *(const float4*)&mids[li*68 + kh_*32 + lg*8 + 4];
#pragma unroll
      for (int e = 0; e < 8; ++e) {
        _Float16 h = (_Float16)mm[e];
        mh[kh_][e] = h; ml[kh_][e] = (_Float16)((mm[e] - (float)h)*2048.f);
      }
    }
    __syncthreads();
    f32x4 h2 = __builtin_amdgcn_mfma_f32_16x16x32_f16(w2h[0], mh[0], Z, 0,0,0);
    h2 = __builtin_amdgcn_mfma_f32_16x16x32_f16(w2h[1], mh[1], h2, 0,0,0);
    f32x4 x2 = __builtin_amdgcn_mfma_f32_16x16x32_f16(w2l[0], mh[0], Z, 0,0,0);
    x2 = __builtin_amdgcn_mfma_f32_16x16x32_f16(w2l[1], mh[1], x2, 0,0,0);
    x2 = __builtin_amdgcn_mfma_f32_16x16x32_f16(w2h[0], ml[0], x2, 0,0,0);
    x2 = __builtin_amdgcn_mfma_f32_16x16x32_f16(w2h[1], ml[1], x2, 0,0,0);
    float rn[4];
    rn[0] = fmaf(x2[0], c2, h2[0]) + boutv.x;
    rn[1] = fmaf(x2[1], c2, h2[1]) + boutv.y;
    rn[2] = fmaf(x2[2], c2, h2[2]) + boutv.z;
    rn[3] = fmaf(x2[3], c2, h2[3]) + boutv.w;
    float ps = rn[0]+rn[1]+rn[2]+rn[3];
    float ps2 = rn[0]*rn[0]+rn[1]*rn[1]+rn[2]*rn[2]+rn[3]*rn[3];
#pragma unroll
    for (int mask = 16; mask <= 32; mask <<= 1) {
      ps  += __shfl_xor(ps,  mask, 64);
      ps2 += __shfl_xor(ps2, mask, 64);
    }
    if (lg == 0) sums[li*4 + wv] = make_float2(ps, ps2);
    __syncthreads();
    float ts = 0.f, ts2 = 0.f;
#pragma unroll
    for (int w = 0; w < 4; ++w) { float2 pp = sums[li*4 + w]; ts += pp.x; ts2 += pp.y; }
    float mu2  = ts*(1.f/64.f);
    float inv2 = rsqrtf(ts2*(1.f/64.f) - mu2*mu2 + 1e-5f);
    float4 xnv = *(const float4*)(x + (size_t)rr*64 + wv*16 + lg*4);
    float4 ov;
    ov.x = (rn[0]-mu2)*inv2*g2v.x + b2v.x + xnv.x;
    ov.y = (rn[1]-mu2)*inv2*g2v.y + b2v.y + xnv.y;
    ov.z = (rn[2]-mu2)*inv2*g2v.z + b2v.z + xnv.z;
    ov.w = (rn[3]-mu2)*inv2*g2v.w + b2v.w + xnv.w;
    *(float4*)&mids[li*68 + wv*16 + lg*4] = ov;
    __syncthreads();
    const int row = tid >> 4, col = (tid & 15)*4;
    *(float4*)(out + (r0 + p*16)*64 + tid*4) = *(const float4*)&mids[row*68 + col];
    __syncthreads();
  }
}

extern "C" void kernel_launch(void* const* d_in, const int* in_sizes, int n_in,
                              void* d_out, int out_size, void* d_ws, size_t ws_size,
                              hipStream_t stream) {
  const float* x    = (const float*)d_in[0];
  const float* Wq   = (const float*)d_in[1];
  const float* Wkv  = (const float*)d_in[2];
  const float* g1   = (const float*)d_in[3];
  const float* b1   = (const float*)d_in[4];
  const float* W1   = (const float*)d_in[5];
  const float* bin  = (const float*)d_in[6];
  const float* W2   = (const float*)d_in[7];
  const float* bout = (const float*)d_in[8];
  const float* g2   = (const float*)d_in[9];
  const float* b2   = (const float*)d_in[10];
  float* ws   = (float*)d_ws;
  float* q    = ws;
  float* k    = ws + 1048576;
  float* v    = ws + 2097152;
  u64*   pk   = (u64*)(ws + 3145728);            // [8][16384] u64 = 1MB
  _Float16* khl = (_Float16*)(ws + 3407872);     // [16384][128] f16 = 4MB

  qkv_kernel<<<ROWS/32, 256, 0, stream>>>(x, Wq, Wkv, q, k, v, khl);
  argmax_mfma_kernel<<<8*JSPLIT*NB, 256, 0, stream>>>(q, khl, pk);
  epilogue_kernel<<<ROWS/32, 256, 0, stream>>>(x, v, q, k, pk, g1, b1, W1, bin,
                                               W2, bout, g2, b2, (float*)d_out);
}

// Round 19
// 52.266 us; speedup vs baseline: 1.0438x; 1.0438x over previous
//
#include <hip/hip_runtime.h>
#include <float.h>

#define NB 8
#define NN 2048
#define ROWS (NB*NN)   // 16384
#define JSPLIT 8
#define JRANGE (NN/JSPLIT)   // 256
#define CHUNK 64
#define NTILE (CHUNK/16)     // 4

typedef _Float16 half8 __attribute__((ext_vector_type(8)));
typedef _Float16 half4 __attribute__((ext_vector_type(4)));
typedef float f32x4 __attribute__((ext_vector_type(4)));
typedef unsigned long long u64;

// monotone f32 -> u32 (order-preserving for all finite floats)
__device__ __forceinline__ unsigned ordf(float f) {
  unsigned u = __float_as_uint(f);
  return (u & 0x80000000u) ? ~u : (u | 0x80000000u);
}

// ---------------- Kernel 1: q,k,v = x @ [Wq|Wkv] via f16 split-3 MFMA ------
__global__ __launch_bounds__(256) void qkv_kernel(
    const float* __restrict__ x, const float* __restrict__ Wq,
    const float* __restrict__ Wkv,
    float* __restrict__ q, float* __restrict__ k, float* __restrict__ v) {
  __shared__ float stage[32*196];   // [r_local][c 0..191], 25KB
  const int tid = threadIdx.x, lane = tid & 63, wv = tid >> 6;
  const int li = lane & 15, lg = lane >> 4;
  const size_t r0 = (size_t)blockIdx.x * 32;
  half8 xh[2][2], xl[2][2];
#pragma unroll
  for (int rt = 0; rt < 2; ++rt)
#pragma unroll
    for (int kh_ = 0; kh_ < 2; ++kh_) {
      const float* src = x + (r0 + rt*16 + li)*64 + kh_*32 + lg*8;
      float4 f0 = *(const float4*)src;
      float4 f1 = *(const float4*)(src+4);
      float vals[8] = {f0.x,f0.y,f0.z,f0.w,f1.x,f1.y,f1.z,f1.w};
#pragma unroll
      for (int e = 0; e < 8; ++e) {
        _Float16 h = (_Float16)vals[e];
        xh[rt][kh_][e] = h;
        xl[rt][kh_][e] = (_Float16)((vals[e] - (float)h) * 2048.0f);
      }
    }
  half8 wh[3][2], wl[3][2];
#pragma unroll
  for (int ci = 0; ci < 3; ++ci) {
    const int ct = wv*3 + ci;
    const int c  = ct*16 + li;
    const float* base; int strideW;
    if (ct < 4) { base = Wq + c; strideW = 64; }
    else        { base = Wkv + (c - 64); strideW = 128; }
#pragma unroll
    for (int kh_ = 0; kh_ < 2; ++kh_) {
      const int kbase = kh_*32 + lg*8;
#pragma unroll
      for (int e = 0; e < 8; ++e) {
        float val = base[(size_t)(kbase + e) * strideW];
        _Float16 h = (_Float16)val;
        wh[ci][kh_][e] = h;
        wl[ci][kh_][e] = (_Float16)((val - (float)h) * 2048.0f);
      }
    }
  }
  const f32x4 Z = {0.f,0.f,0.f,0.f};
#pragma unroll
  for (int rt = 0; rt < 2; ++rt)
#pragma unroll
    for (int ci = 0; ci < 3; ++ci) {
      f32x4 hh = __builtin_amdgcn_mfma_f32_16x16x32_f16(wh[ci][0], xh[rt][0], Z, 0,0,0);
      hh = __builtin_amdgcn_mfma_f32_16x16x32_f16(wh[ci][1], xh[rt][1], hh, 0,0,0);
      f32x4 xx = __builtin_amdgcn_mfma_f32_16x16x32_f16(wl[ci][0], xh[rt][0], Z, 0,0,0);
      xx = __builtin_amdgcn_mfma_f32_16x16x32_f16(wl[ci][1], xh[rt][1], xx, 0,0,0);
      xx = __builtin_amdgcn_mfma_f32_16x16x32_f16(wh[ci][0], xl[rt][0], xx, 0,0,0);
      xx = __builtin_amdgcn_mfma_f32_16x16x32_f16(wh[ci][1], xl[rt][1], xx, 0,0,0);
      const float c2 = 1.0f/2048.0f;
      float s0 = fmaf(xx[0], c2, hh[0]);
      float s1 = fmaf(xx[1], c2, hh[1]);
      float s2 = fmaf(xx[2], c2, hh[2]);
      float s3 = fmaf(xx[3], c2, hh[3]);
      *(float4*)&stage[(rt*16 + li)*196 + (wv*3+ci)*16 + lg*4] = make_float4(s0,s1,s2,s3);
    }
  __syncthreads();
  const size_t obase = r0 * 64;
#pragma unroll
  for (int it = 0; it < 2; ++it) {
    const int off = it*1024 + tid*4;
    const int row = off >> 6, col = off & 63;
    *(float4*)(q + obase + off) = *(const float4*)&stage[row*196 + col];
    *(float4*)(k + obase + off) = *(const float4*)&stage[row*196 + 64 + col];
    *(float4*)(v + obase + off) = *(const float4*)&stage[row*196 + 128 + col];
  }
}

// ---------------- Kernel 2: argmax — R14 body, packed u64 partials ----------
__global__ __launch_bounds__(256,4) void argmax_mfma_kernel(
    const float* __restrict__ q, const float* __restrict__ k,
    u64* __restrict__ pk) {
  __shared__ _Float16 kls[2][8][CHUNK][8];   // [term][d0][j][e] = 16KB
  const int tid = threadIdx.x, lane = tid & 63, wv = tid >> 6;
  const int id = blockIdx.x;
  const int b  = id & 7;              // XCD pin: batch b -> XCD b
  const int ib = (id >> 3) & 7;
  const int js = id >> 6;
  const int i0 = ib*256 + wv*64;      // wave covers 64 i (4 tiles of 16)
  const int lg = lane >> 4, li = lane & 15;
  half8 qh[4][2], ql[4][2];
#pragma unroll
  for (int c = 0; c < 4; ++c)
#pragma unroll
    for (int w = 0; w < 2; ++w) {
      const float* src = q + ((size_t)(b*NN + i0 + c*16 + li))*64 + w*32 + lg*8;
      float4 f0 = *(const float4*)src;
      float4 f1 = *(const float4*)(src+4);
      float vals[8] = {f0.x,f0.y,f0.z,f0.w,f1.x,f1.y,f1.z,f1.w};
#pragma unroll
      for (int e = 0; e < 8; ++e) {
        _Float16 h = (_Float16)vals[e];
        qh[c][w][e] = h;
        ql[c][w][e] = (_Float16)((vals[e] - (float)h) * 2048.0f);
      }
    }
  const f32x4 Z = {0.f,0.f,0.f,0.f};
  float mrun[4] = {-FLT_MAX, -FLT_MAX, -FLT_MAX, -FLT_MAX};
  int   trun[4] = {0, 0, 0, 0};
  const int j0base = js*JRANGE;
#pragma unroll 1
  for (int ch = 0; ch < JRANGE/CHUNK; ++ch) {
    const int j0 = j0base + ch*CHUNK;
    __syncthreads();
#pragma unroll
    for (int it = 0; it < 4; ++it) {     // R11 staging mapping (proven)
      int c = it*256 + tid;
      int j = c & 63, dq = c >> 6;
      const float4 f = *(const float4*)(k + ((size_t)(b*NN + j0 + j))*64 + dq*4);
      float vv[4] = {f.x,f.y,f.z,f.w};
      half4 h, l;
#pragma unroll
      for (int e = 0; e < 4; ++e) {
        _Float16 hh = (_Float16)vv[e];
        h[e] = hh;
        l[e] = (_Float16)((vv[e] - (float)hh) * 2048.0f);
      }
      int d0 = dq >> 1, eo = (dq & 1)*4;
      *(half4*)&kls[0][d0][j][eo] = h;
      *(half4*)&kls[1][d0][j][eo] = l;
    }
    __syncthreads();
#pragma unroll
    for (int jt = 0; jt < NTILE; ++jt) {
      half8 akh0 = *(const half8*)&kls[0][lg  ][jt*16+li][0];
      half8 akh1 = *(const half8*)&kls[0][4+lg][jt*16+li][0];
      half8 akl0 = *(const half8*)&kls[1][lg  ][jt*16+li][0];
      half8 akl1 = *(const half8*)&kls[1][4+lg][jt*16+li][0];
      const int gtile = j0/16 + jt;
#pragma unroll
      for (int c = 0; c < 4; ++c) {
        f32x4 hh = __builtin_amdgcn_mfma_f32_16x16x32_f16(akh0, qh[c][0], Z, 0,0,0);
        hh = __builtin_amdgcn_mfma_f32_16x16x32_f16(akh1, qh[c][1], hh, 0,0,0);
        f32x4 xx = __builtin_amdgcn_mfma_f32_16x16x32_f16(akl0, qh[c][0], Z, 0,0,0);
        xx = __builtin_amdgcn_mfma_f32_16x16x32_f16(akl1, qh[c][1], xx, 0,0,0);
        xx = __builtin_amdgcn_mfma_f32_16x16x32_f16(akh0, ql[c][0], xx, 0,0,0);
        xx = __builtin_amdgcn_mfma_f32_16x16x32_f16(akh1, ql[c][1], xx, 0,0,0);
        const float c2 = 1.0f/2048.0f;
        float s0 = fmaf(xx[0], c2, hh[0]);
        float s1 = fmaf(xx[1], c2, hh[1]);
        float s2 = fmaf(xx[2], c2, hh[2]);
        float s3 = fmaf(xx[3], c2, hh[3]);
        float tmax = fmaxf(fmaxf(s0,s1), fmaxf(s2,s3));
        if (tmax > mrun[c]) { mrun[c] = tmax; trun[c] = gtile; }  // strict >: lowest tile kept
      }
    }
  }
  // pack then cross-lane u64-max (preserves score-then-lowest-tile order)
  u64 key[4];
#pragma unroll
  for (int c = 0; c < 4; ++c)
    key[c] = ((u64)ordf(mrun[c]) << 32) | (unsigned)(127 - trun[c]);
#pragma unroll
  for (int c = 0; c < 4; ++c) {
#pragma unroll
    for (int mask = 16; mask <= 32; mask <<= 1) {
      u64 ok = __shfl_xor(key[c], mask, 64);
      if (ok > key[c]) key[c] = ok;
    }
  }
  {
    const size_t rb = (size_t)js*ROWS + b*NN + i0 + li;
    if (lg == 0)      pk[rb]      = key[0];
    else if (lg == 1) pk[rb + 16] = key[1];
    else if (lg == 2) pk[rb + 32] = key[2];
    else              pk[rb + 48] = key[3];
  }
}

// ---------------- Kernel 3: fused rescue + epilogue (R11 body, u64 reduce) --
__global__ __launch_bounds__(256) void epilogue_kernel(
    const float* __restrict__ x, const float* __restrict__ v,
    const float* __restrict__ q, const float* __restrict__ k,
    const u64* __restrict__ pk,
    const float* __restrict__ g1, const float* __restrict__ b1,
    const float* __restrict__ W1, const float* __restrict__ bin,
    const float* __restrict__ W2, const float* __restrict__ bout,
    const float* __restrict__ g2, const float* __restrict__ b2,
    float* __restrict__ out) {
  __shared__ float mids[16*68];
  __shared__ float2 sums[16*4];
  __shared__ int sidx[32];
  const int tid = threadIdx.x, lane = tid & 63, wv = tid >> 6;
  const int li = lane & 15, lg = lane >> 4;
  const int bid = blockIdx.x;
  const size_t r0 = (size_t)(bid & 7)*NN + (size_t)(bid >> 3)*32;

  // rescue pre-phase: u64-max over 8 js partials, then exact fp32 tile rescue
#pragma unroll
  for (int rnd = 0; rnd < 2; ++rnd) {
    const int rloc = rnd*16 + wv*4 + lg;
    const int row  = (int)r0 + rloc;
    const int b    = row >> 11;
    u64 key = 0ULL;
    if (li < 8) key = pk[(size_t)li*ROWS + row];
#pragma unroll
    for (int mask = 1; mask <= 8; mask <<= 1) {
      u64 ok = __shfl_xor(key, mask, 64);
      if (ok > key) key = ok;
    }
    const int t = 127 - (int)(unsigned)(key & 0xFFFFFFFFu);
    const int j = t*16 + li;
    const float4* qp = (const float4*)(q + (size_t)row*64);
    const float4* kp = (const float4*)(k + ((size_t)(b*NN) + j)*64);
    float a0=0.f,a1=0.f,a2=0.f,a3=0.f;
#pragma unroll
    for (int d4 = 0; d4 < 16; ++d4) {
      float4 qv = qp[d4], kv = kp[d4];
      a0 = fmaf(qv.x,kv.x,a0); a1 = fmaf(qv.y,kv.y,a1);
      a2 = fmaf(qv.z,kv.z,a2); a3 = fmaf(qv.w,kv.w,a3);
    }
    float dot = (a0+a1)+(a2+a3);
    int bj = j;
#pragma unroll
    for (int mask = 1; mask <= 8; mask <<= 1) {
      float od = __shfl_xor(dot, mask, 64);
      int   oj = __shfl_xor(bj, mask, 64);
      if (od > dot || (od == dot && oj < bj)) { dot = od; bj = oj; }  // first max
    }
    if (li == 0) sidx[rloc] = bj;
  }

  half8 wah[2], wal[2], wbh[2], wbl[2], w2h[2], w2l[2];
  const int ocol = wv*16 + li;
#pragma unroll
  for (int kh_ = 0; kh_ < 2; ++kh_) {
#pragma unroll
    for (int e = 0; e < 8; ++e) {
      const int d = kh_*32 + lg*8 + e;
      float wa = W1[d*64 + ocol] + W1[(128+d)*64 + ocol];
      float wb = W1[(64+d)*64 + ocol];
      float w2 = W2[d*64 + ocol];
      _Float16 h;
      h = (_Float16)wa; wah[kh_][e]=h; wal[kh_][e]=(_Float16)((wa-(float)h)*2048.f);
      h = (_Float16)wb; wbh[kh_][e]=h; wbl[kh_][e]=(_Float16)((wb-(float)h)*2048.f);
      h = (_Float16)w2; w2h[kh_][e]=h; w2l[kh_][e]=(_Float16)((w2-(float)h)*2048.f);
    }
  }
  float ga[16], bb[16];
  *(float4*)&ga[0]  = *(const float4*)(g1 + lg*8);
  *(float4*)&ga[4]  = *(const float4*)(g1 + lg*8 + 4);
  *(float4*)&ga[8]  = *(const float4*)(g1 + 32 + lg*8);
  *(float4*)&ga[12] = *(const float4*)(g1 + 32 + lg*8 + 4);
  *(float4*)&bb[0]  = *(const float4*)(b1 + lg*8);
  *(float4*)&bb[4]  = *(const float4*)(b1 + lg*8 + 4);
  *(float4*)&bb[8]  = *(const float4*)(b1 + 32 + lg*8);
  *(float4*)&bb[12] = *(const float4*)(b1 + 32 + lg*8 + 4);
  const float4 binv  = *(const float4*)(bin + wv*16 + lg*4);
  const float4 boutv = *(const float4*)(bout + wv*16 + lg*4);
  const float4 g2v   = *(const float4*)(g2 + wv*16 + lg*4);
  const float4 b2v   = *(const float4*)(b2 + wv*16 + lg*4);
  __syncthreads();   // sidx ready

  const f32x4 Z = {0.f,0.f,0.f,0.f};
  const float c2 = 1.0f/2048.0f;
#pragma unroll 1
  for (int p = 0; p < 2; ++p) {
    const int rr = (int)r0 + p*16 + li;
    const int b  = rr >> 11;
    const int j  = sidx[p*16 + li];
    const float* vsrc = v + ((size_t)b*NN + j)*64 + lg*8;
    const float* xsrc = x + (size_t)rr*64 + lg*8;
    float vv[16], xv[16];
    *(float4*)&vv[0]  = *(const float4*)(vsrc);
    *(float4*)&vv[4]  = *(const float4*)(vsrc+4);
    *(float4*)&vv[8]  = *(const float4*)(vsrc+32);
    *(float4*)&vv[12] = *(const float4*)(vsrc+36);
    *(float4*)&xv[0]  = *(const float4*)(xsrc);
    *(float4*)&xv[4]  = *(const float4*)(xsrc+4);
    *(float4*)&xv[8]  = *(const float4*)(xsrc+32);
    *(float4*)&xv[12] = *(const float4*)(xsrc+36);
    float s = 0.f, s2 = 0.f;
#pragma unroll
    for (int e = 0; e < 16; ++e) { s += vv[e]; s2 += vv[e]*vv[e]; }
#pragma unroll
    for (int mask = 16; mask <= 32; mask <<= 1) {
      s  += __shfl_xor(s,  mask, 64);
      s2 += __shfl_xor(s2, mask, 64);
    }
    float mu  = s*(1.f/64.f);
    float inv = rsqrtf(s2*(1.f/64.f) - mu*mu + 1e-5f);
    half8 nh[2], nl[2], xh[2], xl[2];
#pragma unroll
    for (int kh_ = 0; kh_ < 2; ++kh_)
#pragma unroll
      for (int e = 0; e < 8; ++e) {
        float nvv = (vv[kh_*8+e] - mu)*inv*ga[kh_*8+e] + bb[kh_*8+e];
        _Float16 h = (_Float16)nvv;
        nh[kh_][e] = h; nl[kh_][e] = (_Float16)((nvv - (float)h)*2048.f);
        float xvv = xv[kh_*8+e];
        h = (_Float16)xvv;
        xh[kh_][e] = h; xl[kh_][e] = (_Float16)((xvv - (float)h)*2048.f);
      }
    f32x4 hh = __builtin_amdgcn_mfma_f32_16x16x32_f16(wah[0], nh[0], Z, 0,0,0);
    hh = __builtin_amdgcn_mfma_f32_16x16x32_f16(wah[1], nh[1], hh, 0,0,0);
    hh = __builtin_amdgcn_mfma_f32_16x16x32_f16(wbh[0], xh[0], hh, 0,0,0);
    hh = __builtin_amdgcn_mfma_f32_16x16x32_f16(wbh[1], xh[1], hh, 0,0,0);
    f32x4 xx = __builtin_amdgcn_mfma_f32_16x16x32_f16(wal[0], nh[0], Z, 0,0,0);
    xx = __builtin_amdgcn_mfma_f32_16x16x32_f16(wal[1], nh[1], xx, 0,0,0);
    xx = __builtin_amdgcn_mfma_f32_16x16x32_f16(wah[0], nl[0], xx, 0,0,0);
    xx = __builtin_amdgcn_mfma_f32_16x16x32_f16(wah[1], nl[1], xx, 0,0,0);
    xx = __builtin_amdgcn_mfma_f32_16x16x32_f16(wbl[0], xh[0], xx, 0,0,0);
    xx = __builtin_amdgcn_mfma_f32_16x16x32_f16(wbl[1], xh[1], xx, 0,0,0);
    xx = __builtin_amdgcn_mfma_f32_16x16x32_f16(wbh[0], xl[0], xx, 0,0,0);
    xx = __builtin_amdgcn_mfma_f32_16x16x32_f16(wbh[1], xl[1], xx, 0,0,0);
    float mv0 = fmaxf(fmaf(xx[0], c2, hh[0]) + binv.x, 0.f);
    float mv1 = fmaxf(fmaf(xx[1], c2, hh[1]) + binv.y, 0.f);
    float mv2 = fmaxf(fmaf(xx[2], c2, hh[2]) + binv.z, 0.f);
    float mv3 = fmaxf(fmaf(xx[3], c2, hh[3]) + binv.w, 0.f);
    *(float4*)&mids[li*68 + wv*16 + lg*4] = make_float4(mv0,mv1,mv2,mv3);
    __syncthreads();
    half8 mh[2], ml[2];
#pragma unroll
    for (int kh_ = 0; kh_ < 2; ++kh_) {
      float mm[8];
      *(float4*)&mm[0] = *(const float4*)&mids[li*68 + kh_*32 + lg*8];
      *(float4*)&mm[4] = *(const float4*)&mids[li*68 + kh_*32 + lg*8 + 4];
#pragma unroll
      for (int e = 0; e < 8; ++e) {
        _Float16 h = (_Float16)mm[e];
        mh[kh_][e] = h; ml[kh_][e] = (_Float16)((mm[e] - (float)h)*2048.f);
      }
    }
    __syncthreads();
    f32x4 h2 = __builtin_amdgcn_mfma_f32_16x16x32_f16(w2h[0], mh[0], Z, 0,0,0);
    h2 = __builtin_amdgcn_mfma_f32_16x16x32_f16(w2h[1], mh[1], h2, 0,0,0);
    f32x4 x2 = __builtin_amdgcn_mfma_f32_16x16x32_f16(w2l[0], mh[0], Z, 0,0,0);
    x2 = __builtin_amdgcn_mfma_f32_16x16x32_f16(w2l[1], mh[1], x2, 0,0,0);
    x2 = __builtin_amdgcn_mfma_f32_16x16x32_f16(w2h[0], ml[0], x2, 0,0,0);
    x2 = __builtin_amdgcn_mfma_f32_16x16x32_f16(w2h[1], ml[1], x2, 0,0,0);
    float rn[4];
    rn[0] = fmaf(x2[0], c2, h2[0]) + boutv.x;
    rn[1] = fmaf(x2[1], c2, h2[1]) + boutv.y;
    rn[2] = fmaf(x2[2], c2, h2[2]) + boutv.z;
    rn[3] = fmaf(x2[3], c2, h2[3]) + boutv.w;
    float ps = rn[0]+rn[1]+rn[2]+rn[3];
    float ps2 = rn[0]*rn[0]+rn[1]*rn[1]+rn[2]*rn[2]+rn[3]*rn[3];
#pragma unroll
    for (int mask = 16; mask <= 32; mask <<= 1) {
      ps  += __shfl_xor(ps,  mask, 64);
      ps2 += __shfl_xor(ps2, mask, 64);
    }
    if (lg == 0) sums[li*4 + wv] = make_float2(ps, ps2);
    __syncthreads();
    float ts = 0.f, ts2 = 0.f;
#pragma unroll
    for (int w = 0; w < 4; ++w) { float2 pp = sums[li*4 + w]; ts += pp.x; ts2 += pp.y; }
    float mu2  = ts*(1.f/64.f);
    float inv2 = rsqrtf(ts2*(1.f/64.f) - mu2*mu2 + 1e-5f);
    float4 xnv = *(const float4*)(x + (size_t)rr*64 + wv*16 + lg*4);
    float4 ov;
    ov.x = (rn[0]-mu2)*inv2*g2v.x + b2v.x + xnv.x;
    ov.y = (rn[1]-mu2)*inv2*g2v.y + b2v.y + xnv.y;
    ov.z = (rn[2]-mu2)*inv2*g2v.z + b2v.z + xnv.z;
    ov.w = (rn[3]-mu2)*inv2*g2v.w + b2v.w + xnv.w;
    *(float4*)&mids[li*68 + wv*16 + lg*4] = ov;
    __syncthreads();
    const int row = tid >> 4, col = (tid & 15)*4;
    *(float4*)(out + (r0 + p*16)*64 + tid*4) = *(const float4*)&mids[row*68 + col];
    __syncthreads();
  }
}

extern "C" void kernel_launch(void* const* d_in, const int* in_sizes, int n_in,
                              void* d_out, int out_size, void* d_ws, size_t ws_size,
                              hipStream_t stream) {
  const float* x    = (const float*)d_in[0];
  const float* Wq   = (const float*)d_in[1];
  const float* Wkv  = (const float*)d_in[2];
  const float* g1   = (const float*)d_in[3];
  const float* b1   = (const float*)d_in[4];
  const float* W1   = (const float*)d_in[5];
  const float* bin  = (const float*)d_in[6];
  const float* W2   = (const float*)d_in[7];
  const float* bout = (const float*)d_in[8];
  const float* g2   = (const float*)d_in[9];
  const float* b2   = (const float*)d_in[10];
  float* ws   = (float*)d_ws;
  float* q    = ws;
  float* k    = ws + 1048576;
  float* v    = ws + 2097152;
  u64*   pk   = (u64*)(ws + 3145728);      // [8][16384] u64 = 1MB

  qkv_kernel<<<ROWS/32, 256, 0, stream>>>(x, Wq, Wkv, q, k, v);
  argmax_mfma_kernel<<<8*JSPLIT*NB, 256, 0, stream>>>(q, k, pk);
  epilogue_kernel<<<ROWS/32, 256, 0, stream>>>(x, v, q, k, pk, g1, b1, W1, bin,
                                               W2, bout, g2, b2, (float*)d_out);
}